// Round 8
// baseline (327.187 us; speedup 1.0000x reference)
//
#include <hip/hip_runtime.h>

// Hierarchical 3-level pooled MHA. Round 8: occupancy round.
//  - attn: 8-wave 2-way KV-split + in-block LSE merge, global_load_lds staging
//  - qkv projections merged into one launch (z), single-buf LDS (3 blocks/CU)
//  - final GEMM BM=64 (2 blocks/CU), pools fused to 2 launches
// B=2, S=2048, D=1024, H=16, DH=64.

#define B_  2
#define S_  2048
#define D_  1024
#define H_  16
#define DH_ 64
#define THR2 10.0f

typedef short s8v __attribute__((ext_vector_type(8)));
typedef float f4v __attribute__((ext_vector_type(4)));
typedef float f16v __attribute__((ext_vector_type(16)));
typedef unsigned int u32x2 __attribute__((ext_vector_type(2)));
typedef unsigned int u32x4 __attribute__((ext_vector_type(4)));

__device__ __forceinline__ unsigned cvtpk(float lo, float hi){
    unsigned r;
    asm volatile("v_cvt_pk_bf16_f32 %0, %1, %2" : "=v"(r) : "v"(lo), "v"(hi));
    return r;
}
__device__ __forceinline__ unsigned short f2bf1(float v){
    unsigned r;
    asm volatile("v_cvt_pk_bf16_f32 %0, %1, %2" : "=v"(r) : "v"(v), "v"(v));
    return (unsigned short)r;
}
__device__ __forceinline__ float bf2f(unsigned short h){
    union { unsigned u; float f; } v; v.u = ((unsigned)h) << 16;
    return v.f;
}
__device__ __forceinline__ float exp2_(float x){
    float r; asm("v_exp_f32 %0, %1" : "=v"(r) : "v"(x)); return r;
}
// v_permlane32_swap_b32 vdst, vsrc: vdst[32:63] <-> vsrc[0:31]
__device__ __forceinline__ void pswap(unsigned &dst, unsigned &src){
    asm volatile("v_permlane32_swap_b32 %0, %1" : "+v"(dst), "+v"(src));
}
// XOR-swizzled byte offset of 16B chunk kb in row `row` of a [rows][64bf16] tile.
__device__ __forceinline__ int swz(int row, int kb){
    return row*128 + (((kb) ^ (row & 7) ^ ((row >> 3) & 7)) << 4);
}
// async 16B global->LDS; LDS dest = wave-uniform base + lane*16 (linear)
__device__ __forceinline__ void gld16(const void* g, void* l){
    __builtin_amdgcn_global_load_lds(
        (const __attribute__((address_space(1))) unsigned int*)g,
        (__attribute__((address_space(3))) unsigned int*)l, 16, 0, 0);
}

// ---------------- W transpose + bf16 convert: Wt[n][k] = bf16(W[k][n]) ----------------
__global__ __launch_bounds__(256) void wtrans(
    const float* __restrict__ W0, const float* __restrict__ W1,
    const float* __restrict__ W2, const float* __restrict__ W3,
    unsigned short* __restrict__ T0, unsigned short* __restrict__ T1,
    unsigned short* __restrict__ T2, unsigned short* __restrict__ T3)
{
    __shared__ float tl[32][33];
    const float* W = blockIdx.z==0?W0: blockIdx.z==1?W1: blockIdx.z==2?W2:W3;
    unsigned short* T = blockIdx.z==0?T0: blockIdx.z==1?T1: blockIdx.z==2?T2:T3;
    const int t = threadIdx.x;
    const int bk = blockIdx.x*32, bn = blockIdx.y*32;
    {
        int row = t>>3, c4 = (t&7)*4;
        float4 v = *(const float4*)&W[(size_t)(bk+row)*D_ + bn + c4];
        tl[row][c4+0]=v.x; tl[row][c4+1]=v.y; tl[row][c4+2]=v.z; tl[row][c4+3]=v.w;
    }
    __syncthreads();
    {
        int n = t>>3, k4 = (t&7)*4;
        unsigned a = cvtpk(tl[k4+0][n], tl[k4+1][n]);
        unsigned b = cvtpk(tl[k4+2][n], tl[k4+3][n]);
        u32x2 pk = {a, b};
        *(u32x2*)&T[(size_t)(bn+n)*D_ + bk + k4] = pk;
    }
}

// ---------------- merged Q/K/V projection GEMM (z selects), single-buf LDS ----------------
// C = A_f32[M,K] @ Bt[N,K]^T + bias; mode 1: bf16 [B,H,S,DH]; mode 2: bf16 [B,H,DH,S]
__global__ __launch_bounds__(256, 3) void gemm_qkv(
    const float* __restrict__ Aq, const float* __restrict__ Ak, const float* __restrict__ Avv,
    const unsigned short* __restrict__ Wq_, const unsigned short* __restrict__ Wk_,
    const unsigned short* __restrict__ Wv_,
    const float* __restrict__ bq_, const float* __restrict__ bk_, const float* __restrict__ bv_,
    unsigned short* __restrict__ Oq, unsigned short* __restrict__ Ok,
    unsigned short* __restrict__ Ov, float scale_q)
{
    const int z = blockIdx.z;
    const float* A = z==0?Aq : z==1?Ak : Avv;
    const unsigned short* Btw = z==0?Wq_ : z==1?Wk_ : Wv_;
    const float* bias = z==0?bq_ : z==1?bk_ : bv_;
    unsigned short* C = z==0?Oq : z==1?Ok : Ov;
    const float scale = z==0? scale_q : 1.0f;
    const int mode = (z==2) ? 2 : 1;

    const int N_ = D_, K_ = D_;
    __shared__ __align__(16) char lds[32768];
    char* AsB = lds; char* BsB = lds + 16384;
    const int t = threadIdx.x;
    const int l = t & 63, wv = t>>6, g = l>>4, x = l&15;
    const int wr = wv>>1, wc = wv&1;
    const int br = blockIdx.y*128, bc = blockIdx.x*128;

    int rw[4], bl[4];
    #pragma unroll
    for (int p=0;p<4;++p){ int u = t + 256*p; rw[p] = u>>3; bl[p] = u&7; }

    f4v acc[4][4];
    #pragma unroll
    for (int i=0;i<4;++i)
        #pragma unroll
        for (int j=0;j<4;++j) acc[i][j] = (f4v){0.f,0.f,0.f,0.f};

    float4 alo[4], ahi[4]; s8v brg[4];
    #pragma unroll
    for (int p=0;p<4;++p){
        const float* ap = A + (size_t)(br+rw[p])*K_ + bl[p]*8;
        alo[p] = *(const float4*)ap; ahi[p] = *(const float4*)(ap+4);
        brg[p] = *(const s8v*)(Btw + (size_t)(bc+rw[p])*K_ + bl[p]*8);
    }

    for (int kt=0; kt<K_; kt+=64){
        __syncthreads();   // prev tile LDS reads done
        #pragma unroll
        for (int p=0;p<4;++p){
            uint4 pk;
            pk.x = cvtpk(alo[p].x, alo[p].y); pk.y = cvtpk(alo[p].z, alo[p].w);
            pk.z = cvtpk(ahi[p].x, ahi[p].y); pk.w = cvtpk(ahi[p].z, ahi[p].w);
            *(uint4*)(AsB + swz(rw[p], bl[p])) = pk;
            *(s8v*)(BsB + swz(rw[p], bl[p])) = brg[p];
        }
        __syncthreads();
        if (kt + 64 < K_){
            #pragma unroll
            for (int p=0;p<4;++p){
                const float* ap = A + (size_t)(br+rw[p])*K_ + (kt+64) + bl[p]*8;
                alo[p] = *(const float4*)ap; ahi[p] = *(const float4*)(ap+4);
                brg[p] = *(const s8v*)(Btw + (size_t)(bc+rw[p])*K_ + (kt+64) + bl[p]*8);
            }
        }
        #pragma unroll
        for (int c=0;c<2;++c){
            s8v af[4], bf[4];
            #pragma unroll
            for (int fm=0; fm<4; ++fm)
                af[fm] = *(const s8v*)(AsB + swz(wr*64+fm*16+x, c*4+g));
            #pragma unroll
            for (int fn=0; fn<4; ++fn)
                bf[fn] = *(const s8v*)(BsB + swz(wc*64+fn*16+x, c*4+g));
            __builtin_amdgcn_s_setprio(1);
            #pragma unroll
            for (int fm=0; fm<4; ++fm)
                #pragma unroll
                for (int fn=0; fn<4; ++fn)
                    acc[fm][fn] = __builtin_amdgcn_mfma_f32_16x16x32_bf16(
                        af[fm], bf[fn], acc[fm][fn], 0,0,0);
            __builtin_amdgcn_s_setprio(0);
        }
    }

    #pragma unroll
    for (int fn=0; fn<4; ++fn){
        int col = bc + wc*64 + fn*16 + x;
        float bv = bias[col];
        #pragma unroll
        for (int fm=0; fm<4; ++fm){
            int row0 = br + wr*64 + fm*16 + g*4;
            float v0 = acc[fm][fn][0] + bv;
            float v1 = acc[fm][fn][1] + bv;
            float v2 = acc[fm][fn][2] + bv;
            float v3 = acc[fm][fn][3] + bv;
            if (mode == 1){
                int hI = col>>6, dhI = col & (DH_-1);
                #pragma unroll
                for (int r=0;r<4;++r){
                    int row = row0 + r;
                    int bI = row>>11, sI = row & (S_-1);
                    float vv = (r==0?v0: r==1?v1: r==2?v2: v3) * scale;
                    C[(((size_t)(bI*H_+hI))*S_+sI)*DH_+dhI] = f2bf1(vv);
                }
            } else {  // mode 2: [B,H,DH,S]
                int bI = row0>>11, sI = row0 & (S_-1);
                int hI = col>>6, dhI = col & (DH_-1);
                u32x2 pk;
                pk.x = cvtpk(v0*scale, v1*scale);
                pk.y = cvtpk(v2*scale, v3*scale);
                *(u32x2*)&C[(((size_t)(bI*H_+hI))*DH_+dhI)*S_ + sI] = pk;
            }
        }
    }
}

// ---------------- final GEMM: out_f32 = A_bf16 @ Bt^T + bias; BM=64, BN=128 ----------------
__global__ __launch_bounds__(256, 2) void gemm_out(
    const unsigned short* __restrict__ Ab, const unsigned short* __restrict__ Btw,
    const float* __restrict__ bias, float* __restrict__ C)
{
    const int N_ = D_, K_ = D_;
    __shared__ __align__(16) char lds[24576];
    char* AsB = lds;           // A[64][64] bf16 swizzled, 8KB
    char* BsB = lds + 8192;    // B[128][64] bf16 swizzled, 16KB
    const int t = threadIdx.x, l = t&63, wv = t>>6, g = l>>4, x = l&15;
    const int br = blockIdx.y*64, bc = blockIdx.x*128;

    int arw[2], abl[2];
    #pragma unroll
    for (int p=0;p<2;++p){ int u = t + 256*p; arw[p] = u>>3; abl[p] = u&7; }
    int brw[4], bbl[4];
    #pragma unroll
    for (int p=0;p<4;++p){ int u = t + 256*p; brw[p] = u>>3; bbl[p] = u&7; }

    f4v acc[4][2];
    #pragma unroll
    for (int i=0;i<4;++i){ acc[i][0] = (f4v){0,0,0,0}; acc[i][1] = (f4v){0,0,0,0}; }

    s8v arg[2], brg[4];
    #pragma unroll
    for (int p=0;p<2;++p) arg[p] = *(const s8v*)(Ab + (size_t)(br+arw[p])*K_ + abl[p]*8);
    #pragma unroll
    for (int p=0;p<4;++p) brg[p] = *(const s8v*)(Btw + (size_t)(bc+brw[p])*K_ + bbl[p]*8);

    for (int kt=0; kt<K_; kt+=64){
        __syncthreads();
        #pragma unroll
        for (int p=0;p<2;++p) *(s8v*)(AsB + swz(arw[p], abl[p])) = arg[p];
        #pragma unroll
        for (int p=0;p<4;++p) *(s8v*)(BsB + swz(brw[p], bbl[p])) = brg[p];
        __syncthreads();
        if (kt + 64 < K_){
            #pragma unroll
            for (int p=0;p<2;++p)
                arg[p] = *(const s8v*)(Ab + (size_t)(br+arw[p])*K_ + (kt+64) + abl[p]*8);
            #pragma unroll
            for (int p=0;p<4;++p)
                brg[p] = *(const s8v*)(Btw + (size_t)(bc+brw[p])*K_ + (kt+64) + bbl[p]*8);
        }
        #pragma unroll
        for (int c=0;c<2;++c){
            s8v af[4], bf[2];
            #pragma unroll
            for (int fm=0; fm<4; ++fm)
                af[fm] = *(const s8v*)(AsB + swz(fm*16+x, c*4+g));
            #pragma unroll
            for (int fn=0; fn<2; ++fn)
                bf[fn] = *(const s8v*)(BsB + swz(wv*32+fn*16+x, c*4+g));
            __builtin_amdgcn_s_setprio(1);
            #pragma unroll
            for (int fm=0; fm<4; ++fm)
                #pragma unroll
                for (int fn=0; fn<2; ++fn)
                    acc[fm][fn] = __builtin_amdgcn_mfma_f32_16x16x32_bf16(
                        af[fm], bf[fn], acc[fm][fn], 0,0,0);
            __builtin_amdgcn_s_setprio(0);
        }
    }

    #pragma unroll
    for (int fn=0; fn<2; ++fn){
        int col = bc + wv*32 + fn*16 + x;
        float bv = bias[col];
        #pragma unroll
        for (int fm=0; fm<4; ++fm){
            int row0 = br + fm*16 + g*4;
            #pragma unroll
            for (int r=0;r<4;++r)
                C[(size_t)(row0+r)*N_ + col] = acc[fm][fn][r] + bv;
        }
    }
}

// ---------------- fused pools (z=0: K pool [BH][S][DH]; z=1: V pool [BH*DH][S]) ----------------
__global__ __launch_bounds__(256) void pool_pair(
    const unsigned short* __restrict__ kin, unsigned short* __restrict__ kout,
    const unsigned short* __restrict__ vin, unsigned short* __restrict__ vout,
    int nOut4, int Sin, int shift)
{
    int idx = blockIdx.x * 256 + threadIdx.x;
    if (idx >= nOut4) return;
    if (blockIdx.z == 0){
        int d0 = (idx & 15) * 4;
        int rest = idx >> 4;
        int Sout = Sin >> 1;
        int so = rest % Sout, bh = rest / Sout;
        size_t base = ((size_t)bh * Sin + 2*so) * DH_ + d0;
        ushort4 a = *(const ushort4*)&kin[base];
        ushort4 c = *(const ushort4*)&kin[base + DH_];
        ushort4 o;
        o.x = f2bf1(0.5f*(bf2f(a.x)+bf2f(c.x)));
        o.y = f2bf1(0.5f*(bf2f(a.y)+bf2f(c.y)));
        o.z = f2bf1(0.5f*(bf2f(a.z)+bf2f(c.z)));
        o.w = f2bf1(0.5f*(bf2f(a.w)+bf2f(c.w)));
        *(ushort4*)&kout[(size_t)idx*4] = o;
    } else {
        int row = idx >> shift;
        int so4 = (idx & ((1<<shift)-1)) << 2;
        union { u32x4 u; unsigned short hh[8]; } a;
        a.u = *(const u32x4*)&vin[(size_t)row*Sin + so4*2];
        float m0 = 0.5f*(bf2f(a.hh[0])+bf2f(a.hh[1]));
        float m1 = 0.5f*(bf2f(a.hh[2])+bf2f(a.hh[3]));
        float m2 = 0.5f*(bf2f(a.hh[4])+bf2f(a.hh[5]));
        float m3 = 0.5f*(bf2f(a.hh[6])+bf2f(a.hh[7]));
        u32x2 pk; pk.x = cvtpk(m0,m1); pk.y = cvtpk(m2,m3);
        *(u32x2*)&vout[(size_t)row*(Sin>>1) + so4] = pk;
    }
}

// ---------------- MFMA flash attention v6: 8 waves, 2-way KV split ----------------
// Waves wq (half 0) and wq+4 (half 1) own the same 32 q-rows; half h processes
// KV tiles 2t+h; per-level LSE merge through LDS. Staging via global_load_lds
// (linear LDS dest, inverse-swizzled per-lane global source; swz on read).
__global__ __launch_bounds__(512, 4) void attn_mfma6(
    const unsigned short* __restrict__ qh,
    const unsigned short* __restrict__ kh0, const unsigned short* __restrict__ kh1,
    const unsigned short* __restrict__ kh2,
    const unsigned short* __restrict__ vt0, const unsigned short* __restrict__ vt1,
    const unsigned short* __restrict__ vt2,
    const float* __restrict__ wlv, unsigned short* __restrict__ accOut)
{
    __shared__ __align__(16) char lds[65536];  // [cur][parity]: K 8K + V 8K per region
    const int t = threadIdx.x, l = t&63, wv = t>>6;
    const int q = l&31, hi = l>>5;
    const int half = wv>>2, wq = wv&3;
    const int bid = blockIdx.x;
    const int qt = bid & 15, h = (bid>>4)&(H_-1), b = bid>>8;

    const float w0=wlv[0], w1=wlv[1], w2=wlv[2];
    const float winv = 1.f/(w0+w1+w2);

    const unsigned short* qp =
        qh + (((size_t)(b*H_+h))*S_ + (size_t)qt*128 + wq*32 + q)*DH_ + hi*8;
    s8v qf0 = *(const s8v*)(qp);
    s8v qf1 = *(const s8v*)(qp+16);
    s8v qf2 = *(const s8v*)(qp+32);
    s8v qf3 = *(const s8v*)(qp+48);

    // staging role: wq 0,1 -> K rows [0-31],[32-63]; wq 2,3 -> V rows ditto
    const int lr = l>>3, lc = l&7;
    const int isV = (wq>>1)&1;
    const int wbase = (wq&1)*32, wb8 = (wq&1)*4;
    int chs[4];
    #pragma unroll
    for (int j=0;j<4;++j) chs[j] = lc ^ lr ^ ((wb8 + j)&7);
    int koff[4];   // K: byte offset within K tile (rows stride DH)
    #pragma unroll
    for (int j=0;j<4;++j) koff[j] = ((wbase + j*8 + lr)*DH_ + chs[j]*8)*2;

    f16v accO0, accO1;
    #pragma unroll
    for (int r=0;r<16;++r){ accO0[r]=0.f; accO1[r]=0.f; }

    int cur = 0;
    #pragma unroll 1
    for (int lvl=0; lvl<3; ++lvl){
        const unsigned short *kp, *vp; int nt; float wgt;
        if (lvl==0)      { kp = kh0; vp = vt0; nt = 32; wgt = w0; }
        else if (lvl==1) { kp = kh1; vp = vt1; nt = 16; wgt = w1; }
        else             { kp = kh2; vp = vt2; nt = 8;  wgt = w2; }
        const int Sl = nt*64;
        const char* gK = (const char*)(kp + (size_t)(b*H_+h)*Sl*DH_);
        const char* gV = (const char*)(vp + (size_t)(b*H_+h)*DH_*Sl);
        int voff[4];   // V^T: rows = dh, stride Sl
        #pragma unroll
        for (int j=0;j<4;++j) voff[j] = ((wbase + j*8 + lr)*Sl + chs[j]*8)*2;

        float m_i = -1e30f, l_i = 0.f;
        f16v o0, o1;
        #pragma unroll
        for (int r=0;r<16;++r){ o0[r]=0.f; o1[r]=0.f; }

        const int nt2 = nt>>1;
        {   // prologue: tile = half -> buf[cur][half]
            char* lb0 = lds + cur*32768 + half*16384 + isV*8192;
            const char* g0 = isV ? (gV + half*128) : (gK + half*8192);
            const int* off = isV ? voff : koff;
            #pragma unroll
            for (int j=0;j<4;++j)
                gld16(g0 + off[j], lb0 + (wbase + j*8)*128);
        }
        #pragma unroll 1
        for (int rd=0; rd<nt2; ++rd){
            asm volatile("s_waitcnt vmcnt(0)" ::: "memory");
            __syncthreads();      // all groups' loads into cur landed
            if (rd+1 < nt2){      // T14: next tile's loads fly under compute
                int tile = 2*(rd+1) + half;
                char* lb1 = lds + (cur^1)*32768 + half*16384 + isV*8192;
                const char* g1 = isV ? (gV + tile*128) : (gK + tile*8192);
                const int* off = isV ? voff : koff;
                #pragma unroll
                for (int j=0;j<4;++j)
                    gld16(g1 + off[j], lb1 + (wbase + j*8)*128);
            }
            char* kb_ = lds + cur*32768 + half*16384;
            char* vb_ = kb_ + 8192;

            // ---- S^T = K @ Q^T ----
            f16v s0, s1;
            #pragma unroll
            for (int r=0;r<16;++r){ s0[r]=0.f; s1[r]=0.f; }
            {
                s8v k00 = *(const s8v*)(kb_ + swz(q,      0*2+hi));
                s8v k01 = *(const s8v*)(kb_ + swz(q,      1*2+hi));
                s8v k02 = *(const s8v*)(kb_ + swz(q,      2*2+hi));
                s8v k03 = *(const s8v*)(kb_ + swz(q,      3*2+hi));
                s8v k10 = *(const s8v*)(kb_ + swz(32+q,   0*2+hi));
                s8v k11 = *(const s8v*)(kb_ + swz(32+q,   1*2+hi));
                s8v k12 = *(const s8v*)(kb_ + swz(32+q,   2*2+hi));
                s8v k13 = *(const s8v*)(kb_ + swz(32+q,   3*2+hi));
                __builtin_amdgcn_s_setprio(1);
                s0 = __builtin_amdgcn_mfma_f32_32x32x16_bf16(k00, qf0, s0, 0,0,0);
                s1 = __builtin_amdgcn_mfma_f32_32x32x16_bf16(k10, qf0, s1, 0,0,0);
                s0 = __builtin_amdgcn_mfma_f32_32x32x16_bf16(k01, qf1, s0, 0,0,0);
                s1 = __builtin_amdgcn_mfma_f32_32x32x16_bf16(k11, qf1, s1, 0,0,0);
                s0 = __builtin_amdgcn_mfma_f32_32x32x16_bf16(k02, qf2, s0, 0,0,0);
                s1 = __builtin_amdgcn_mfma_f32_32x32x16_bf16(k12, qf2, s1, 0,0,0);
                s0 = __builtin_amdgcn_mfma_f32_32x32x16_bf16(k03, qf3, s0, 0,0,0);
                s1 = __builtin_amdgcn_mfma_f32_32x32x16_bf16(k13, qf3, s1, 0,0,0);
                __builtin_amdgcn_s_setprio(0);
            }

            // ---- online softmax (exp2, defer-max) ----
            float pm;
            {
                float a0 = fmaxf(fmaxf(s0[0],s0[1]),   fmaxf(s0[2],s0[3]));
                float a1 = fmaxf(fmaxf(s0[4],s0[5]),   fmaxf(s0[6],s0[7]));
                float a2 = fmaxf(fmaxf(s0[8],s0[9]),   fmaxf(s0[10],s0[11]));
                float a3 = fmaxf(fmaxf(s0[12],s0[13]), fmaxf(s0[14],s0[15]));
                float a4 = fmaxf(fmaxf(s1[0],s1[1]),   fmaxf(s1[2],s1[3]));
                float a5 = fmaxf(fmaxf(s1[4],s1[5]),   fmaxf(s1[6],s1[7]));
                float a6 = fmaxf(fmaxf(s1[8],s1[9]),   fmaxf(s1[10],s1[11]));
                float a7 = fmaxf(fmaxf(s1[12],s1[13]), fmaxf(s1[14],s1[15]));
                pm = fmaxf(fmaxf(fmaxf(a0,a1),fmaxf(a2,a3)),
                           fmaxf(fmaxf(a4,a5),fmaxf(a6,a7)));
            }
            pm = fmaxf(pm, __shfl_xor(pm, 32, 64));
            if (__any(pm > m_i + THR2)) {
                float mn = fmaxf(m_i, pm);
                float corr = exp2_(m_i - mn);
                m_i = mn;
                l_i *= corr;
                #pragma unroll
                for (int r=0;r<16;++r){
                    float cb = __shfl(corr, ((r&3)+8*(r>>2)) + 4*hi, 64);
                    o0[r] *= cb; o1[r] *= cb;
                }
            }
            float rs = 0.f;
            #pragma unroll
            for (int r=0;r<16;++r){ s0[r] = exp2_(s0[r]-m_i); rs += s0[r]; }
            #pragma unroll
            for (int r=0;r<16;++r){ s1[r] = exp2_(s1[r]-m_i); rs += s1[r]; }
            rs += __shfl_xor(rs, 32, 64);
            l_i += rs;

            // ---- P-frags in-register (cvt_pk + permlane32_swap) ----
            unsigned a0 = cvtpk(s0[0], s0[1]),  a1 = cvtpk(s0[2], s0[3]);
            unsigned b0 = cvtpk(s0[4], s0[5]),  b1 = cvtpk(s0[6], s0[7]);
            pswap(a0, b0); pswap(a1, b1);
            unsigned c0 = cvtpk(s0[8], s0[9]),  c1 = cvtpk(s0[10], s0[11]);
            unsigned d0 = cvtpk(s0[12], s0[13]),d1 = cvtpk(s0[14], s0[15]);
            pswap(c0, d0); pswap(c1, d1);
            unsigned e0 = cvtpk(s1[0], s1[1]),  e1 = cvtpk(s1[2], s1[3]);
            unsigned f0 = cvtpk(s1[4], s1[5]),  f1 = cvtpk(s1[6], s1[7]);
            pswap(e0, f0); pswap(e1, f1);
            unsigned g0 = cvtpk(s1[8], s1[9]),  g1 = cvtpk(s1[10], s1[11]);
            unsigned h0 = cvtpk(s1[12], s1[13]),h1 = cvtpk(s1[14], s1[15]);
            pswap(g0, h0); pswap(g1, h1);
            union { u32x4 u; s8v s; } pf0, pf1, pf2, pf3;
            pf0.u = (u32x4){a0, a1, b0, b1};
            pf1.u = (u32x4){c0, c1, d0, d1};
            pf2.u = (u32x4){e0, e1, f0, f1};
            pf3.u = (u32x4){g0, g1, h0, h1};

            // ---- O += P @ V ----
            {
                s8v v00 = *(const s8v*)(vb_ + swz(q,    0*2+hi));
                s8v v01 = *(const s8v*)(vb_ + swz(q,    1*2+hi));
                s8v v02 = *(const s8v*)(vb_ + swz(q,    2*2+hi));
                s8v v03 = *(const s8v*)(vb_ + swz(q,    3*2+hi));
                s8v v10 = *(const s8v*)(vb_ + swz(32+q, 0*2+hi));
                s8v v11 = *(const s8v*)(vb_ + swz(32+q, 1*2+hi));
                s8v v12 = *(const s8v*)(vb_ + swz(32+q, 2*2+hi));
                s8v v13 = *(const s8v*)(vb_ + swz(32+q, 3*2+hi));
                __builtin_amdgcn_s_setprio(1);
                o0 = __builtin_amdgcn_mfma_f32_32x32x16_bf16(pf0.s, v00, o0, 0,0,0);
                o1 = __builtin_amdgcn_mfma_f32_32x32x16_bf16(pf0.s, v10, o1, 0,0,0);
                o0 = __builtin_amdgcn_mfma_f32_32x32x16_bf16(pf1.s, v01, o0, 0,0,0);
                o1 = __builtin_amdgcn_mfma_f32_32x32x16_bf16(pf1.s, v11, o1, 0,0,0);
                o0 = __builtin_amdgcn_mfma_f32_32x32x16_bf16(pf2.s, v02, o0, 0,0,0);
                o1 = __builtin_amdgcn_mfma_f32_32x32x16_bf16(pf2.s, v12, o1, 0,0,0);
                o0 = __builtin_amdgcn_mfma_f32_32x32x16_bf16(pf3.s, v03, o0, 0,0,0);
                o1 = __builtin_amdgcn_mfma_f32_32x32x16_bf16(pf3.s, v13, o1, 0,0,0);
                __builtin_amdgcn_s_setprio(0);
            }
            cur ^= 1;
        }

        // ---- cross-half LSE merge (scratch overlaps staging; barrier-guarded) ----
        float wl = wgt * winv;
        __syncthreads();                        // all compute on staging done
        if (half == 1){
            char* scr = lds;
            #pragma unroll
            for (int g4=0; g4<4; ++g4){
                float4 a; a.x=o0[g4*4+0]; a.y=o0[g4*4+1]; a.z=o0[g4*4+2]; a.w=o0[g4*4+3];
                *(float4*)(scr + wq*4096 + g4*1024 + l*16) = a;
                float4 c; c.x=o1[g4*4+0]; c.y=o1[g4*4+1]; c.z=o1[g4*4+2]; c.w=o1[g4*4+3];
                *(float4*)(scr + 16384 + wq*4096 + g4*1024 + l*16) = c;
            }
            *(float*)(lds + 32768 + wq*256 + l*4) = m_i;
            *(float*)(lds + 33792 + wq*256 + l*4) = l_i;
        }
        __syncthreads();
        if (half == 0){
            char* scr = lds;
            float mp = *(const float*)(lds + 32768 + wq*256 + l*4);
            float lp = *(const float*)(lds + 33792 + wq*256 + l*4);
            float mm  = fmaxf(m_i, mp);
            float ca  = exp2_(m_i - mm);
            float cb2 = exp2_(mp  - mm);
            float lm  = l_i*ca + lp*cb2;
            float po0[16], po1[16];
            #pragma unroll
            for (int g4=0; g4<4; ++g4){
                float4 a = *(const float4*)(scr + wq*4096 + g4*1024 + l*16);
                po0[g4*4+0]=a.x; po0[g4*4+1]=a.y; po0[g4*4+2]=a.z; po0[g4*4+3]=a.w;
                float4 c = *(const float4*)(scr + 16384 + wq*4096 + g4*1024 + l*16);
                po1[g4*4+0]=c.x; po1[g4*4+1]=c.y; po1[g4*4+2]=c.z; po1[g4*4+3]=c.w;
            }
            #pragma unroll
            for (int r=0;r<16;++r){
                int qr = ((r&3)+8*(r>>2)) + 4*hi;
                float caB = __shfl(ca,  qr, 64);
                float cbB = __shfl(cb2, qr, 64);
                float lB  = __shfl(lm,  qr, 64);
                float sc = wl / lB;
                accO0[r] += (o0[r]*caB + po0[r]*cbB) * sc;
                accO1[r] += (o1[r]*caB + po1[r]*cbB) * sc;
            }
        }
        __syncthreads();                        // merge reads done before next staging
    }

    if (half == 0){
        #pragma unroll
        for (int r=0;r<16;++r){
            int qrow = ((r&3)+8*(r>>2)) + 4*hi;
            size_t row = (size_t)b*S_ + (size_t)qt*128 + wq*32 + qrow;
            accOut[row*D_ + h*DH_ + q]      = f2bf1(accO0[r]);
            accOut[row*D_ + h*DH_ + 32 + q] = f2bf1(accO1[r]);
        }
    }
}

// ---------------- launch ----------------
extern "C" void kernel_launch(void* const* d_in, const int* in_sizes, int n_in,
                              void* d_out, int out_size, void* d_ws, size_t ws_size,
                              hipStream_t stream)
{
    const float* query = (const float*)d_in[0];
    const float* key   = (const float*)d_in[1];
    const float* value = (const float*)d_in[2];
    const float* Wq = (const float*)d_in[3];  const float* bq = (const float*)d_in[4];
    const float* Wk = (const float*)d_in[5];  const float* bk = (const float*)d_in[6];
    const float* Wv = (const float*)d_in[7];  const float* bv = (const float*)d_in[8];
    const float* Wo = (const float*)d_in[9];  const float* bo = (const float*)d_in[10];
    const float* wlv = (const float*)d_in[11];

    char* w = (char*)d_ws;
    unsigned short* qhb  = (unsigned short*)(w);             // 8 MB [B,H,S,DH]
    unsigned short* khb0 = (unsigned short*)(w + 8388608);   // 8 MB [B,H,S,DH]
    unsigned short* khb1 = (unsigned short*)(w + 16777216);  // 4 MB
    unsigned short* khb2 = (unsigned short*)(w + 20971520);  // 2 MB
    unsigned short* vtb0 = (unsigned short*)(w + 23068672);  // 8 MB [B,H,DH,S]
    unsigned short* vtb1 = (unsigned short*)(w + 31457280);  // 4 MB
    unsigned short* vtb2 = (unsigned short*)(w + 35651584);  // 2 MB
    unsigned short* accb = (unsigned short*)(w + 37748736);  // 8 MB [B,S,D]
    unsigned short* Wtq  = (unsigned short*)(w + 46137344);  // 2 MB each
    unsigned short* Wtk  = (unsigned short*)(w + 48234496);
    unsigned short* Wtv  = (unsigned short*)(w + 50331648);
    unsigned short* Wto  = (unsigned short*)(w + 52428800);  // end 54525952

    dim3 bb(256);
    wtrans<<<dim3(32,32,4), bb, 0, stream>>>(Wq, Wk, Wv, Wo, Wtq, Wtk, Wtv, Wto);

    const float scale_q = 0.125f * 1.44269504088896f;   // 1/sqrt(DH) * log2(e)
    gemm_qkv<<<dim3(8,32,3), bb, 0, stream>>>(query, key, value,
                                              Wtq, Wtk, Wtv, bq, bk, bv,
                                              qhb, khb0, vtb0, scale_q);

    int n1 = B_ * H_ * (S_/2) * DH_ / 4;   // 524288
    int n2 = B_ * H_ * (S_/4) * DH_ / 4;   // 262144
    pool_pair<<<dim3(n1/256,1,2), bb, 0, stream>>>(khb0, khb1, vtb0, vtb1, n1, S_,   8);
    pool_pair<<<dim3(n2/256,1,2), bb, 0, stream>>>(khb1, khb2, vtb1, vtb2, n2, S_/2, 7);

    attn_mfma6<<<512, 512, 0, stream>>>(qhb, khb0, khb1, khb2,
                                        vtb0, vtb1, vtb2, wlv, accb);

    gemm_out<<<dim3(8,64), bb, 0, stream>>>(accb, Wto, bo, (float*)d_out);
}

// Round 9
// 194.031 us; speedup vs baseline: 1.6863x; 1.6863x over previous
//
#include <hip/hip_runtime.h>

// Hierarchical 3-level pooled MHA. Round 9: R7 attention body, level-split
// across blocks (y=0: level 0 -> acc0; y=1: levels 1,2 -> acc1) for 2x wave
// occupancy with no merge logic. Final GEMM sums the two bf16 partials during
// staging. All other kernels = R7 proven versions; pools fused to 2 launches.
// B=2, S=2048, D=1024, H=16, DH=64.

#define B_  2
#define S_  2048
#define D_  1024
#define H_  16
#define DH_ 64
#define THR2 10.0f   // defer-max threshold, base-2 domain

typedef short s8v __attribute__((ext_vector_type(8)));    // 8 bf16
typedef float f4v __attribute__((ext_vector_type(4)));
typedef float f16v __attribute__((ext_vector_type(16)));  // 32x32 accum
typedef unsigned int u32x2 __attribute__((ext_vector_type(2)));
typedef unsigned int u32x4 __attribute__((ext_vector_type(4)));

__device__ __forceinline__ unsigned cvtpk(float lo, float hi){
    unsigned r;
    asm volatile("v_cvt_pk_bf16_f32 %0, %1, %2" : "=v"(r) : "v"(lo), "v"(hi));
    return r;
}
__device__ __forceinline__ unsigned short f2bf1(float v){
    unsigned r;
    asm volatile("v_cvt_pk_bf16_f32 %0, %1, %2" : "=v"(r) : "v"(v), "v"(v));
    return (unsigned short)r;
}
__device__ __forceinline__ float bf2f(unsigned short h){
    union { unsigned u; float f; } v; v.u = ((unsigned)h) << 16;
    return v.f;
}
__device__ __forceinline__ float exp2_(float x){
    float r; asm("v_exp_f32 %0, %1" : "=v"(r) : "v"(x)); return r;
}
// v_permlane32_swap_b32 vdst, vsrc: vdst[32:63] <-> vsrc[0:31] (both updated).
__device__ __forceinline__ void pswap(unsigned &dst, unsigned &src){
    asm volatile("v_permlane32_swap_b32 %0, %1" : "+v"(dst), "+v"(src));
}
// bf16x2 + bf16x2 -> bf16x2 (exact f32 adds, RNE repack)
__device__ __forceinline__ unsigned addpk(unsigned x, unsigned y){
    union { unsigned u; float f; } a, b, c, d;
    a.u = x << 16;          b.u = y << 16;
    c.u = x & 0xFFFF0000u;  d.u = y & 0xFFFF0000u;
    return cvtpk(a.f + b.f, c.f + d.f);
}
// XOR-swizzled byte offset of 16B block kb in row `row` of a [rows][64bf16] tile.
__device__ __forceinline__ int swz(int row, int kb){
    return row*128 + (((kb) ^ (row & 7) ^ ((row >> 3) & 7)) << 4);
}

// ---------------- W transpose + bf16 convert: Wt[n][k] = bf16(W[k][n]) ----------------
__global__ __launch_bounds__(256) void wtrans(
    const float* __restrict__ W0, const float* __restrict__ W1,
    const float* __restrict__ W2, const float* __restrict__ W3,
    unsigned short* __restrict__ T0, unsigned short* __restrict__ T1,
    unsigned short* __restrict__ T2, unsigned short* __restrict__ T3)
{
    __shared__ float tl[32][33];
    const float* W = blockIdx.z==0?W0: blockIdx.z==1?W1: blockIdx.z==2?W2:W3;
    unsigned short* T = blockIdx.z==0?T0: blockIdx.z==1?T1: blockIdx.z==2?T2:T3;
    const int t = threadIdx.x;
    const int bk = blockIdx.x*32, bn = blockIdx.y*32;
    {
        int row = t>>3, c4 = (t&7)*4;
        float4 v = *(const float4*)&W[(size_t)(bk+row)*D_ + bn + c4];
        tl[row][c4+0]=v.x; tl[row][c4+1]=v.y; tl[row][c4+2]=v.z; tl[row][c4+3]=v.w;
    }
    __syncthreads();
    {
        int n = t>>3, k4 = (t&7)*4;
        unsigned a = cvtpk(tl[k4+0][n], tl[k4+1][n]);
        unsigned b = cvtpk(tl[k4+2][n], tl[k4+3][n]);
        u32x2 pk = {a, b};
        *(u32x2*)&T[(size_t)(bn+n)*D_ + bk + k4] = pk;
    }
}

// ---------------- bf16 MFMA GEMM (R7): C = A_f32[M,K] @ Bt[N,K]^T + bias ----------------
// MODE 1: bf16 head-major [B,H,S,DH], *scale. MODE 2: bf16 [B,H,DH,S], *scale.
template<int MODE>
__global__ __launch_bounds__(256) void gemm_proj(
    const float* __restrict__ Af, const unsigned short* __restrict__ Btw,
    const float* __restrict__ bias, unsigned short* __restrict__ C, float scale)
{
    const int N_ = D_, K_ = D_;
    __shared__ __align__(16) char lds[65536];    // dbuf: [cur][A 16K | B 16K]
    const int t = threadIdx.x;
    const int l = t & 63, wv = t>>6, g = l>>4, x = l&15;
    const int wr = wv>>1, wc = wv&1;
    const int br = blockIdx.y*128, bc = blockIdx.x*128;

    int rw[4], bl[4];
    #pragma unroll
    for (int p=0;p<4;++p){ int u = t + 256*p; rw[p] = u>>3; bl[p] = u&7; }

    f4v acc[4][4];
    #pragma unroll
    for (int i=0;i<4;++i)
        #pragma unroll
        for (int j=0;j<4;++j) acc[i][j] = (f4v){0.f,0.f,0.f,0.f};

    float4 alo[4], ahi[4]; s8v brg[4];
    #pragma unroll
    for (int p=0;p<4;++p){
        const float* ap = Af + (size_t)(br+rw[p])*K_ + bl[p]*8;
        alo[p] = *(const float4*)ap; ahi[p] = *(const float4*)(ap+4);
        brg[p] = *(const s8v*)(Btw + (size_t)(bc+rw[p])*K_ + bl[p]*8);
    }

    int cur = 0;
    for (int kt=0; kt<K_; kt+=64){
        char* AsB = lds + cur*32768;
        char* BsB = AsB + 16384;
        #pragma unroll
        for (int p=0;p<4;++p){
            uint4 pk;
            pk.x = cvtpk(alo[p].x, alo[p].y); pk.y = cvtpk(alo[p].z, alo[p].w);
            pk.z = cvtpk(ahi[p].x, ahi[p].y); pk.w = cvtpk(ahi[p].z, ahi[p].w);
            *(uint4*)(AsB + swz(rw[p], bl[p])) = pk;
            *(s8v*)(BsB + swz(rw[p], bl[p])) = brg[p];
        }
        if (kt + 64 < K_){
            #pragma unroll
            for (int p=0;p<4;++p){
                const float* ap = Af + (size_t)(br+rw[p])*K_ + (kt+64) + bl[p]*8;
                alo[p] = *(const float4*)ap; ahi[p] = *(const float4*)(ap+4);
                brg[p] = *(const s8v*)(Btw + (size_t)(bc+rw[p])*K_ + (kt+64) + bl[p]*8);
            }
        }
        __syncthreads();
        #pragma unroll
        for (int c=0;c<2;++c){
            s8v af[4], bf[4];
            #pragma unroll
            for (int fm=0; fm<4; ++fm)
                af[fm] = *(const s8v*)(AsB + swz(wr*64+fm*16+x, c*4+g));
            #pragma unroll
            for (int fn=0; fn<4; ++fn)
                bf[fn] = *(const s8v*)(BsB + swz(wc*64+fn*16+x, c*4+g));
            __builtin_amdgcn_s_setprio(1);
            #pragma unroll
            for (int fm=0; fm<4; ++fm)
                #pragma unroll
                for (int fn=0; fn<4; ++fn)
                    acc[fm][fn] = __builtin_amdgcn_mfma_f32_16x16x32_bf16(
                        af[fm], bf[fn], acc[fm][fn], 0,0,0);
            __builtin_amdgcn_s_setprio(0);
        }
        cur ^= 1;
    }

    #pragma unroll
    for (int fn=0; fn<4; ++fn){
        int col = bc + wc*64 + fn*16 + x;
        float bv = bias[col];
        #pragma unroll
        for (int fm=0; fm<4; ++fm){
            int row0 = br + wr*64 + fm*16 + g*4;
            float v0 = acc[fm][fn][0] + bv;
            float v1 = acc[fm][fn][1] + bv;
            float v2 = acc[fm][fn][2] + bv;
            float v3 = acc[fm][fn][3] + bv;
            if (MODE == 1){
                int hI = col>>6, dhI = col & (DH_-1);
                #pragma unroll
                for (int r=0;r<4;++r){
                    int row = row0 + r;
                    int bI = row>>11, sI = row & (S_-1);
                    float vv = (r==0?v0: r==1?v1: r==2?v2: v3) * scale;
                    C[(((size_t)(bI*H_+hI))*S_+sI)*DH_+dhI] = f2bf1(vv);
                }
            } else {  // MODE 2: [B,H,DH,S]
                int bI = row0>>11, sI = row0 & (S_-1);
                int hI = col>>6, dhI = col & (DH_-1);
                u32x2 pk;
                pk.x = cvtpk(v0*scale, v1*scale);
                pk.y = cvtpk(v2*scale, v3*scale);
                *(u32x2*)&C[(((size_t)(bI*H_+hI))*DH_+dhI)*S_ + sI] = pk;
            }
        }
    }
}

// ---------------- final GEMM: out_f32 = (acc0+acc1)_bf16 @ Wto^T + bias ----------------
__global__ __launch_bounds__(256) void gemm_sum(
    const unsigned short* __restrict__ A0, const unsigned short* __restrict__ A1,
    const unsigned short* __restrict__ Btw, const float* __restrict__ bias,
    float* __restrict__ C)
{
    const int N_ = D_, K_ = D_;
    __shared__ __align__(16) char lds[65536];
    const int t = threadIdx.x;
    const int l = t & 63, wv = t>>6, g = l>>4, x = l&15;
    const int wr = wv>>1, wc = wv&1;
    const int br = blockIdx.y*128, bc = blockIdx.x*128;

    int rw[4], bl[4];
    #pragma unroll
    for (int p=0;p<4;++p){ int u = t + 256*p; rw[p] = u>>3; bl[p] = u&7; }

    f4v acc[4][4];
    #pragma unroll
    for (int i=0;i<4;++i)
        #pragma unroll
        for (int j=0;j<4;++j) acc[i][j] = (f4v){0.f,0.f,0.f,0.f};

    u32x4 a0r[4], a1r[4]; s8v brg[4];
    #pragma unroll
    for (int p=0;p<4;++p){
        a0r[p] = *(const u32x4*)(A0 + (size_t)(br+rw[p])*K_ + bl[p]*8);
        a1r[p] = *(const u32x4*)(A1 + (size_t)(br+rw[p])*K_ + bl[p]*8);
        brg[p] = *(const s8v*)(Btw + (size_t)(bc+rw[p])*K_ + bl[p]*8);
    }

    int cur = 0;
    for (int kt=0; kt<K_; kt+=64){
        char* AsB = lds + cur*32768;
        char* BsB = AsB + 16384;
        #pragma unroll
        for (int p=0;p<4;++p){
            uint4 pk;
            pk.x = addpk(a0r[p].x, a1r[p].x);
            pk.y = addpk(a0r[p].y, a1r[p].y);
            pk.z = addpk(a0r[p].z, a1r[p].z);
            pk.w = addpk(a0r[p].w, a1r[p].w);
            *(uint4*)(AsB + swz(rw[p], bl[p])) = pk;
            *(s8v*)(BsB + swz(rw[p], bl[p])) = brg[p];
        }
        if (kt + 64 < K_){
            #pragma unroll
            for (int p=0;p<4;++p){
                a0r[p] = *(const u32x4*)(A0 + (size_t)(br+rw[p])*K_ + (kt+64) + bl[p]*8);
                a1r[p] = *(const u32x4*)(A1 + (size_t)(br+rw[p])*K_ + (kt+64) + bl[p]*8);
                brg[p] = *(const s8v*)(Btw + (size_t)(bc+rw[p])*K_ + (kt+64) + bl[p]*8);
            }
        }
        __syncthreads();
        #pragma unroll
        for (int c=0;c<2;++c){
            s8v af[4], bf[4];
            #pragma unroll
            for (int fm=0; fm<4; ++fm)
                af[fm] = *(const s8v*)(AsB + swz(wr*64+fm*16+x, c*4+g));
            #pragma unroll
            for (int fn=0; fn<4; ++fn)
                bf[fn] = *(const s8v*)(BsB + swz(wc*64+fn*16+x, c*4+g));
            __builtin_amdgcn_s_setprio(1);
            #pragma unroll
            for (int fm=0; fm<4; ++fm)
                #pragma unroll
                for (int fn=0; fn<4; ++fn)
                    acc[fm][fn] = __builtin_amdgcn_mfma_f32_16x16x32_bf16(
                        af[fm], bf[fn], acc[fm][fn], 0,0,0);
            __builtin_amdgcn_s_setprio(0);
        }
        cur ^= 1;
    }

    #pragma unroll
    for (int fn=0; fn<4; ++fn){
        int col = bc + wc*64 + fn*16 + x;
        float bv = bias[col];
        #pragma unroll
        for (int fm=0; fm<4; ++fm){
            int row0 = br + wr*64 + fm*16 + g*4;
            #pragma unroll
            for (int r=0;r<4;++r)
                C[(size_t)(row0+r)*N_ + col] = acc[fm][fn][r] + bv;
        }
    }
}

// ---------------- fused pools (z=0: K pool [BH][S][DH]; z=1: V pool [BH*DH][S]) ----------------
__global__ __launch_bounds__(256) void pool_pair(
    const unsigned short* __restrict__ kin, unsigned short* __restrict__ kout,
    const unsigned short* __restrict__ vin, unsigned short* __restrict__ vout,
    int nOut4, int Sin, int shift)
{
    int idx = blockIdx.x * 256 + threadIdx.x;
    if (idx >= nOut4) return;
    if (blockIdx.z == 0){
        int d0 = (idx & 15) * 4;
        int rest = idx >> 4;
        int Sout = Sin >> 1;
        int so = rest % Sout, bh = rest / Sout;
        size_t base = ((size_t)bh * Sin + 2*so) * DH_ + d0;
        ushort4 a = *(const ushort4*)&kin[base];
        ushort4 c = *(const ushort4*)&kin[base + DH_];
        ushort4 o;
        o.x = f2bf1(0.5f*(bf2f(a.x)+bf2f(c.x)));
        o.y = f2bf1(0.5f*(bf2f(a.y)+bf2f(c.y)));
        o.z = f2bf1(0.5f*(bf2f(a.z)+bf2f(c.z)));
        o.w = f2bf1(0.5f*(bf2f(a.w)+bf2f(c.w)));
        *(ushort4*)&kout[(size_t)idx*4] = o;
    } else {
        int row = idx >> shift;
        int so4 = (idx & ((1<<shift)-1)) << 2;
        union { u32x4 u; unsigned short hh[8]; } a;
        a.u = *(const u32x4*)&vin[(size_t)row*Sin + so4*2];
        float m0 = 0.5f*(bf2f(a.hh[0])+bf2f(a.hh[1]));
        float m1 = 0.5f*(bf2f(a.hh[2])+bf2f(a.hh[3]));
        float m2 = 0.5f*(bf2f(a.hh[4])+bf2f(a.hh[5]));
        float m3 = 0.5f*(bf2f(a.hh[6])+bf2f(a.hh[7]));
        u32x2 pk; pk.x = cvtpk(m0,m1); pk.y = cvtpk(m2,m3);
        *(u32x2*)&vout[(size_t)row*(Sin>>1) + so4] = pk;
    }
}

// ---------------- MFMA flash attention (R7 body, level-split by blockIdx.y) ----------------
// y=0: level 0 -> acc0 (weight w0/sum). y=1: levels 1,2 -> acc1.
// 4 waves x 32 q-rows; KV tile 64, dbuf, 1 barrier/tile; in-register P.
__global__ __launch_bounds__(256, 2) void attn_mfma7(
    const unsigned short* __restrict__ qh,
    const unsigned short* __restrict__ kh0, const unsigned short* __restrict__ kh1,
    const unsigned short* __restrict__ kh2,
    const unsigned short* __restrict__ vt0, const unsigned short* __restrict__ vt1,
    const unsigned short* __restrict__ vt2,
    const float* __restrict__ wlv,
    unsigned short* __restrict__ acc0, unsigned short* __restrict__ acc1)
{
    __shared__ __align__(16) char ksm[2][8192];   // K  [key][dh] swizzled
    __shared__ __align__(16) char vsm[2][8192];   // V^T [dh][key] swizzled
    const int t = threadIdx.x, l = t&63, wv = t>>6, q = l&31, hi = l>>5;
    const int bid = blockIdx.x;
    const int qt = bid & 15, h = (bid>>4) & (H_-1), b = bid >> 8;
    const int grp = blockIdx.y;
    const int lvB = grp ? 1 : 0, lvE = grp ? 3 : 1;
    unsigned short* accOut = grp ? acc1 : acc0;

    const float w0 = wlv[0], w1 = wlv[1], w2 = wlv[2];
    const float winv = 1.f/(w0+w1+w2);

    // Q fragments (B-operand): qf[dc][j] = Q[q][dc*16 + hi*8 + j]
    const unsigned short* qp =
        qh + (((size_t)(b*H_+h))*S_ + (size_t)qt*128 + wv*32 + q)*DH_ + hi*8;
    s8v qf0 = *(const s8v*)(qp);
    s8v qf1 = *(const s8v*)(qp + 16);
    s8v qf2 = *(const s8v*)(qp + 32);
    s8v qf3 = *(const s8v*)(qp + 48);

    // staging: thread covers rows r0 and r0+32, 16B block kb (same offs K and V^T)
    const int r0 = t>>3, kb = t&7;
    const int off0 = swz(r0, kb), off1 = swz(r0+32, kb);

    f16v aO0, aO1;
    #pragma unroll
    for (int r=0;r<16;++r){ aO0[r]=0.f; aO1[r]=0.f; }

    int cur = 0;
    #pragma unroll 1
    for (int lvl = lvB; lvl < lvE; ++lvl) {
        const unsigned short *kp, *vpt; int nt; float wc;
        if (lvl == 0)      { kp = kh0; vpt = vt0; nt = 32; wc = w0; }
        else if (lvl == 1) { kp = kh1; vpt = vt1; nt = 16; wc = w1; }
        else               { kp = kh2; vpt = vt2; nt = 8;  wc = w2; }
        const int Sl = nt*64;
        const unsigned short* kbase = kp + (size_t)(b*H_+h)*Sl*DH_;
        const unsigned short* v0r = vpt + ((size_t)(b*H_+h)*DH_ + r0)*Sl;
        const unsigned short* v1r = vpt + ((size_t)(b*H_+h)*DH_ + r0+32)*Sl;

        float m_i = -1e30f, l_i = 0.f;
        f16v o0, o1;
        #pragma unroll
        for (int r=0;r<16;++r){ o0[r]=0.f; o1[r]=0.f; }

        // prologue: tile 0 -> regs
        s8v krg0 = *(const s8v*)(kbase + (size_t)r0*DH_ + kb*8);
        s8v krg1 = *(const s8v*)(kbase + (size_t)(r0+32)*DH_ + kb*8);
        s8v vrg0 = *(const s8v*)(v0r + kb*8);
        s8v vrg1 = *(const s8v*)(v1r + kb*8);

        for (int kt = 0; kt < nt; ++kt) {
            char* kb_ = ksm[cur];
            char* vb_ = vsm[cur];
            *(s8v*)(kb_ + off0) = krg0;
            *(s8v*)(kb_ + off1) = krg1;
            *(s8v*)(vb_ + off0) = vrg0;
            *(s8v*)(vb_ + off1) = vrg1;
            if (kt + 1 < nt) {
                size_t nb = (size_t)(kt+1)*64;
                krg0 = *(const s8v*)(kbase + (nb+r0)*DH_ + kb*8);
                krg1 = *(const s8v*)(kbase + (nb+r0+32)*DH_ + kb*8);
                vrg0 = *(const s8v*)(v0r + nb + kb*8);
                vrg1 = *(const s8v*)(v1r + nb + kb*8);
            }
            __syncthreads();

            // ---- S^T = K @ Q^T (base-2 scaled) ----
            f16v s0, s1;
            #pragma unroll
            for (int r=0;r<16;++r){ s0[r]=0.f; s1[r]=0.f; }
            {
                s8v k00 = *(const s8v*)(kb_ + swz(q,      0*2+hi));
                s8v k01 = *(const s8v*)(kb_ + swz(q,      1*2+hi));
                s8v k02 = *(const s8v*)(kb_ + swz(q,      2*2+hi));
                s8v k03 = *(const s8v*)(kb_ + swz(q,      3*2+hi));
                s8v k10 = *(const s8v*)(kb_ + swz(32+q,   0*2+hi));
                s8v k11 = *(const s8v*)(kb_ + swz(32+q,   1*2+hi));
                s8v k12 = *(const s8v*)(kb_ + swz(32+q,   2*2+hi));
                s8v k13 = *(const s8v*)(kb_ + swz(32+q,   3*2+hi));
                __builtin_amdgcn_s_setprio(1);
                s0 = __builtin_amdgcn_mfma_f32_32x32x16_bf16(k00, qf0, s0, 0,0,0);
                s1 = __builtin_amdgcn_mfma_f32_32x32x16_bf16(k10, qf0, s1, 0,0,0);
                s0 = __builtin_amdgcn_mfma_f32_32x32x16_bf16(k01, qf1, s0, 0,0,0);
                s1 = __builtin_amdgcn_mfma_f32_32x32x16_bf16(k11, qf1, s1, 0,0,0);
                s0 = __builtin_amdgcn_mfma_f32_32x32x16_bf16(k02, qf2, s0, 0,0,0);
                s1 = __builtin_amdgcn_mfma_f32_32x32x16_bf16(k12, qf2, s1, 0,0,0);
                s0 = __builtin_amdgcn_mfma_f32_32x32x16_bf16(k03, qf3, s0, 0,0,0);
                s1 = __builtin_amdgcn_mfma_f32_32x32x16_bf16(k13, qf3, s1, 0,0,0);
                __builtin_amdgcn_s_setprio(0);
            }

            // ---- online softmax (exp2 domain, defer-max); lane owns one q ----
            float pm = s0[0];
            #pragma unroll
            for (int r=1;r<16;++r) pm = fmaxf(pm, s0[r]);
            #pragma unroll
            for (int r=0;r<16;++r) pm = fmaxf(pm, s1[r]);
            pm = fmaxf(pm, __shfl_xor(pm, 32, 64));
            if (__any(pm > m_i + THR2)) {
                float mn = fmaxf(m_i, pm);
                float corr = exp2_(m_i - mn);
                m_i = mn;
                l_i *= corr;
                #pragma unroll
                for (int r=0;r<16;++r){
                    float cb = __shfl(corr, ((r&3)+8*(r>>2)) + 4*hi, 64);
                    o0[r] *= cb; o1[r] *= cb;
                }
            }
            float rs = 0.f;
            #pragma unroll
            for (int r=0;r<16;++r){ s0[r] = exp2_(s0[r]-m_i); rs += s0[r]; }
            #pragma unroll
            for (int r=0;r<16;++r){ s1[r] = exp2_(s1[r]-m_i); rs += s1[r]; }
            rs += __shfl_xor(rs, 32, 64);
            l_i += rs;

            // ---- P-frags in-register: cvt_pk pairs + permlane32_swap ----
            unsigned a0 = cvtpk(s0[0], s0[1]),  a1 = cvtpk(s0[2], s0[3]);
            unsigned b0 = cvtpk(s0[4], s0[5]),  b1 = cvtpk(s0[6], s0[7]);
            pswap(a0, b0); pswap(a1, b1);
            unsigned c0 = cvtpk(s0[8], s0[9]),  c1 = cvtpk(s0[10], s0[11]);
            unsigned d0 = cvtpk(s0[12], s0[13]),d1 = cvtpk(s0[14], s0[15]);
            pswap(c0, d0); pswap(c1, d1);
            unsigned e0 = cvtpk(s1[0], s1[1]),  e1 = cvtpk(s1[2], s1[3]);
            unsigned f0 = cvtpk(s1[4], s1[5]),  f1 = cvtpk(s1[6], s1[7]);
            pswap(e0, f0); pswap(e1, f1);
            unsigned g0 = cvtpk(s1[8], s1[9]),  g1 = cvtpk(s1[10], s1[11]);
            unsigned h0 = cvtpk(s1[12], s1[13]),h1 = cvtpk(s1[14], s1[15]);
            pswap(g0, h0); pswap(g1, h1);
            union { u32x4 u; s8v s; } pf0, pf1, pf2, pf3;
            pf0.u = (u32x4){a0, a1, b0, b1};
            pf1.u = (u32x4){c0, c1, d0, d1};
            pf2.u = (u32x4){e0, e1, f0, f1};
            pf3.u = (u32x4){g0, g1, h0, h1};

            // ---- O += P @ V (V^T-frags from LDS) ----
            {
                s8v v00 = *(const s8v*)(vb_ + swz(q,    0*2+hi));
                s8v v01 = *(const s8v*)(vb_ + swz(q,    1*2+hi));
                s8v v02 = *(const s8v*)(vb_ + swz(q,    2*2+hi));
                s8v v03 = *(const s8v*)(vb_ + swz(q,    3*2+hi));
                s8v v10 = *(const s8v*)(vb_ + swz(32+q, 0*2+hi));
                s8v v11 = *(const s8v*)(vb_ + swz(32+q, 1*2+hi));
                s8v v12 = *(const s8v*)(vb_ + swz(32+q, 2*2+hi));
                s8v v13 = *(const s8v*)(vb_ + swz(32+q, 3*2+hi));
                __builtin_amdgcn_s_setprio(1);
                o0 = __builtin_amdgcn_mfma_f32_32x32x16_bf16(pf0.s, v00, o0, 0,0,0);
                o1 = __builtin_amdgcn_mfma_f32_32x32x16_bf16(pf0.s, v10, o1, 0,0,0);
                o0 = __builtin_amdgcn_mfma_f32_32x32x16_bf16(pf1.s, v01, o0, 0,0,0);
                o1 = __builtin_amdgcn_mfma_f32_32x32x16_bf16(pf1.s, v11, o1, 0,0,0);
                o0 = __builtin_amdgcn_mfma_f32_32x32x16_bf16(pf2.s, v02, o0, 0,0,0);
                o1 = __builtin_amdgcn_mfma_f32_32x32x16_bf16(pf2.s, v12, o1, 0,0,0);
                o0 = __builtin_amdgcn_mfma_f32_32x32x16_bf16(pf3.s, v03, o0, 0,0,0);
                o1 = __builtin_amdgcn_mfma_f32_32x32x16_bf16(pf3.s, v13, o1, 0,0,0);
                __builtin_amdgcn_s_setprio(0);
            }
            cur ^= 1;
        }

        float wl = wc * winv;
        #pragma unroll
        for (int r=0;r<16;++r){
            float lb = __shfl(l_i, ((r&3)+8*(r>>2)) + 4*hi, 64);
            float sc = wl / lb;
            aO0[r] += o0[r] * sc;
            aO1[r] += o1[r] * sc;
        }
    }

    #pragma unroll
    for (int r=0;r<16;++r){
        int qrow = ((r&3)+8*(r>>2)) + 4*hi;
        size_t row = (size_t)b*S_ + (size_t)qt*128 + wv*32 + qrow;
        accOut[row*D_ + h*DH_ + q]      = f2bf1(aO0[r]);
        accOut[row*D_ + h*DH_ + 32 + q] = f2bf1(aO1[r]);
    }
}

// ---------------- launch ----------------
extern "C" void kernel_launch(void* const* d_in, const int* in_sizes, int n_in,
                              void* d_out, int out_size, void* d_ws, size_t ws_size,
                              hipStream_t stream)
{
    const float* query = (const float*)d_in[0];
    const float* key   = (const float*)d_in[1];
    const float* value = (const float*)d_in[2];
    const float* Wq = (const float*)d_in[3];  const float* bq = (const float*)d_in[4];
    const float* Wk = (const float*)d_in[5];  const float* bk = (const float*)d_in[6];
    const float* Wv = (const float*)d_in[7];  const float* bv = (const float*)d_in[8];
    const float* Wo = (const float*)d_in[9];  const float* bo = (const float*)d_in[10];
    const float* wlv = (const float*)d_in[11];

    char* w = (char*)d_ws;
    unsigned short* qhb  = (unsigned short*)(w);             // 8 MB [B,H,S,DH]
    unsigned short* khb0 = (unsigned short*)(w + 8388608);   // 8 MB [B,H,S,DH]
    unsigned short* khb1 = (unsigned short*)(w + 16777216);  // 4 MB
    unsigned short* khb2 = (unsigned short*)(w + 20971520);  // 2 MB
    unsigned short* vtb0 = (unsigned short*)(w + 23068672);  // 8 MB [B,H,DH,S]
    unsigned short* vtb1 = (unsigned short*)(w + 31457280);  // 4 MB
    unsigned short* vtb2 = (unsigned short*)(w + 35651584);  // 2 MB
    unsigned short* acc0 = (unsigned short*)(w + 37748736);  // 8 MB [B,S,D] partial lvl0
    unsigned short* Wto  = (unsigned short*)(w + 46137344);  // 2 MB
    unsigned short* Wtq  = (unsigned short*)(w + 48234496);  // 2 MB (dead after proj)
    unsigned short* Wtk  = (unsigned short*)(w + 50331648);  // 2 MB (dead after proj)
    unsigned short* Wtv  = (unsigned short*)(w + 52428800);  // 2 MB (dead after proj)
    unsigned short* acc1 = (unsigned short*)(w + 48234496);  // 8 MB, overlaps Wtq..Wtv+2MB
                                                             // (attn runs after projections)
    // total ws use: 56,623,104 bytes

    dim3 bb(256);
    wtrans<<<dim3(32,32,4), bb, 0, stream>>>(Wq, Wk, Wv, Wo, Wtq, Wtk, Wtv, Wto);

    const float scale_q = 0.125f * 1.44269504088896f;   // 1/sqrt(DH) * log2(e)
    dim3 gg(D_/128, (B_*S_)/128);
    gemm_proj<1><<<gg, bb, 0, stream>>>(query, Wtq, bq, qhb,  scale_q);
    gemm_proj<1><<<gg, bb, 0, stream>>>(key,   Wtk, bk, khb0, 1.0f);
    gemm_proj<2><<<gg, bb, 0, stream>>>(value, Wtv, bv, vtb0, 1.0f);

    int n1 = B_ * H_ * (S_/2) * DH_ / 4;   // 524288
    int n2 = B_ * H_ * (S_/4) * DH_ / 4;   // 262144
    pool_pair<<<dim3(n1/256,1,2), bb, 0, stream>>>(khb0, khb1, vtb0, vtb1, n1, S_,   8);
    pool_pair<<<dim3(n2/256,1,2), bb, 0, stream>>>(khb1, khb2, vtb1, vtb2, n2, S_/2, 7);

    attn_mfma7<<<dim3(512, 2), bb, 0, stream>>>(qhb, khb0, khb1, khb2,
                                                vtb0, vtb1, vtb2, wlv, acc0, acc1);

    gemm_sum<<<gg, bb, 0, stream>>>(acc0, acc1, Wto, bo, (float*)d_out);
}